// Round 1
// baseline (271.236 us; speedup 1.0000x reference)
//
#include <hip/hip_runtime.h>

#define NN 100000
#define NE 1250000
#define HD 64

#define CAP_L3   4096
#define CAP_L2   65536
#define CAP_L1   262144
#define CAP_NL2  4096
#define CAP_NL1  65536
#define CAP_NL0  262144

// ctrl indices: 0=cntL3 1=cntL2 2=cntL1 3=cntNL2 4=cntNL1 5=cntNL0 6=cntPL(=2)

__global__ void k_init(float* norm_out, float* norm_in, unsigned* flags,
                       int* ctrl, int* PL, const int* __restrict__ pair) {
    int i = blockIdx.x * blockDim.x + threadIdx.x;
    if (i < NN) {
        norm_out[i] = 0.f;
        norm_in[i]  = 0.f;
        int p0 = pair[0], p1 = pair[1];
        flags[i] = (i == p0 || i == p1) ? 8u : 0u;
    }
    if (i < 16) ctrl[i] = (i == 6) ? 2 : 0;
    if (i == 0) { PL[0] = pair[0]; PL[1] = pair[1]; }
}

// degrees for all nodes + level-3 scan (edges into {pair nodes}), mark T2 sources
__global__ void k_deg_scan3(const int* __restrict__ src, const int* __restrict__ dst,
                            float* norm_out, float* norm_in, unsigned* flags,
                            int* L3, int* NL2, int* ctrl) {
    int e = blockIdx.x * blockDim.x + threadIdx.x;
    if (e >= NE) return;
    int s = src[e], d = dst[e];
    atomicAdd(&norm_out[s], 1.0f);
    atomicAdd(&norm_in[d], 1.0f);
    if (flags[d] & 8u) {   // bit3 stable during this kernel (only bit2 is OR'd)
        int idx = atomicAdd(&ctrl[0], 1);
        if (idx < CAP_L3) L3[idx] = e;
        unsigned old = atomicOr(&flags[s], 4u);
        if (!(old & 4u)) { int j = atomicAdd(&ctrl[3], 1); if (j < CAP_NL2) NL2[j] = s; }
    }
}

__global__ void k_norm(float* norm_out, float* norm_in) {
    int i = blockIdx.x * blockDim.x + threadIdx.x;
    if (i < NN) {
        norm_out[i] = 1.0f / sqrtf(fmaxf(norm_out[i], 1.0f));
        norm_in[i]  = 1.0f / sqrtf(fmaxf(norm_in[i], 1.0f));
    }
}

// generic frontier scan: collect edges whose dst carries testmask, mark srcs with setmask
__global__ void k_scan(const int* __restrict__ src, const int* __restrict__ dst,
                       unsigned* flags, unsigned testmask, unsigned setmask,
                       int* L, int cntL_idx, int capL,
                       int* NL, int cntNL_idx, int capNL, int* ctrl) {
    int e = blockIdx.x * blockDim.x + threadIdx.x;
    if (e >= NE) return;
    int d = dst[e];
    if (flags[d] & testmask) {   // testmask bit not modified during this kernel
        int s = src[e];
        int idx = atomicAdd(&ctrl[cntL_idx], 1);
        if (idx < capL) L[idx] = e;
        unsigned old = atomicOr(&flags[s], setmask);
        if (!(old & setmask)) {
            int j = atomicAdd(&ctrl[cntNL_idx], 1);
            if (j < capNL) NL[j] = s;
        }
    }
}

// x0 = z_table[z[v]] for T0 nodes into bufA; zero T1 rows of bufB (agg target)
__global__ void k_prep(const int* __restrict__ NL0, const int* __restrict__ NL1,
                       const int* __restrict__ ctrl, const int* __restrict__ z,
                       const float* __restrict__ zt, float* bufA, float* bufB) {
    int c0 = min(ctrl[5], CAP_NL0);
    int c1 = min(ctrl[4], CAP_NL1);
    int total = (c0 + c1) * HD;
    for (int t = blockIdx.x * blockDim.x + threadIdx.x; t < total;
         t += gridDim.x * blockDim.x) {
        int r = t >> 6, lane = t & 63;
        if (r < c0) { int v = NL0[r]; bufA[v * HD + lane] = zt[z[v] * HD + lane]; }
        else        { int v = NL1[r - c0]; bufB[v * HD + lane] = 0.0f; }
    }
}

__global__ void k_zero_rows(const int* __restrict__ NL, const int* __restrict__ ctrl,
                            int cnt_idx, int cap, float* buf) {
    int cnt = min(ctrl[cnt_idx], cap);
    int total = cnt * HD;
    for (int t = blockIdx.x * blockDim.x + threadIdx.x; t < total;
         t += gridDim.x * blockDim.x) {
        int v = NL[t >> 6];
        buf[v * HD + (t & 63)] = 0.0f;
    }
}

// agg[d] += norm_out[s] * xin[s] over collected edge list
__global__ void k_scatter(const int* __restrict__ L, const int* __restrict__ ctrl,
                          int cnt_idx, int cap,
                          const int* __restrict__ src, const int* __restrict__ dst,
                          const float* __restrict__ norm_out,
                          const float* __restrict__ xin, float* agg) {
    int cnt = min(ctrl[cnt_idx], cap);
    int total = cnt * HD;
    for (int t = blockIdx.x * blockDim.x + threadIdx.x; t < total;
         t += gridDim.x * blockDim.x) {
        int e = L[t >> 6], lane = t & 63;
        int s = src[e], d = dst[e];
        atomicAdd(&agg[d * HD + lane], norm_out[s] * xin[s * HD + lane]);
    }
}

// row-wise: buf[v] = (buf[v]*norm_in[v]) @ W + b  (optional relu), wave per row
__global__ __launch_bounds__(256) void k_gemm(const int* __restrict__ NL,
                                              const int* __restrict__ ctrl,
                                              int cnt_idx, int cap,
                                              const float* __restrict__ norm_in,
                                              float* buf,
                                              const float* __restrict__ W,
                                              const float* __restrict__ bias,
                                              int do_relu) {
    int cnt = min(ctrl[cnt_idx], cap);
    int gtid = blockIdx.x * blockDim.x + threadIdx.x;
    int wave = gtid >> 6, lane = gtid & 63;
    int nw = (gridDim.x * blockDim.x) >> 6;
    float wb = bias[lane];
    for (int r = wave; r < cnt; r += nw) {
        int v = NL[r];
        float a = buf[v * HD + lane] * norm_in[v];
        float acc = wb;
#pragma unroll
        for (int i = 0; i < HD; ++i)
            acc += __shfl(a, i, 64) * W[i * HD + lane];
        buf[v * HD + lane] = do_relu ? fmaxf(acc, 0.0f) : acc;
    }
}

// h = x3[p0]*x3[p1]; t = relu(h@lin1+b1); out = t@lin2 + b2
__global__ void k_final(const float* __restrict__ bufB, const int* __restrict__ pair,
                        const float* __restrict__ l1w, const float* __restrict__ l1b,
                        const float* __restrict__ l2w, const float* __restrict__ l2b,
                        float* out) {
    int lane = threadIdx.x;  // 64 threads
    float h = bufB[pair[0] * HD + lane] * bufB[pair[1] * HD + lane];
    float t = l1b[lane];
#pragma unroll
    for (int i = 0; i < HD; ++i)
        t += __shfl(h, i, 64) * l1w[i * HD + lane];
    t = fmaxf(t, 0.0f);
    float val = t * l2w[lane];
#pragma unroll
    for (int off = 32; off; off >>= 1)
        val += __shfl_down(val, off, 64);
    if (lane == 0) out[0] = val + l2b[0];
}

extern "C" void kernel_launch(void* const* d_in, const int* in_sizes, int n_in,
                              void* d_out, int out_size, void* d_ws, size_t ws_size,
                              hipStream_t stream) {
    const int*   z    = (const int*)d_in[0];
    const int*   src  = (const int*)d_in[1];
    const int*   dst  = (const int*)d_in[2];
    const int*   pair = (const int*)d_in[3];
    const float* zt   = (const float*)d_in[4];
    const float* W1   = (const float*)d_in[5];
    const float* b1   = (const float*)d_in[6];
    const float* W2   = (const float*)d_in[7];
    const float* b2   = (const float*)d_in[8];
    const float* W3   = (const float*)d_in[9];
    const float* b3   = (const float*)d_in[10];
    const float* l1w  = (const float*)d_in[11];
    const float* l1b  = (const float*)d_in[12];
    const float* l2w  = (const float*)d_in[13];
    const float* l2b  = (const float*)d_in[14];
    float* out = (float*)d_out;

    char* w = (char*)d_ws;
    auto alloc = [&](size_t bytes) {
        char* p = w;
        w += (bytes + 255) & ~(size_t)255;
        return p;
    };
    float*    bufA     = (float*)alloc((size_t)NN * HD * 4);
    float*    bufB     = (float*)alloc((size_t)NN * HD * 4);
    float*    norm_out = (float*)alloc((size_t)NN * 4);
    float*    norm_in  = (float*)alloc((size_t)NN * 4);
    unsigned* flags    = (unsigned*)alloc((size_t)NN * 4);
    int*      L3       = (int*)alloc((size_t)CAP_L3 * 4);
    int*      L2       = (int*)alloc((size_t)CAP_L2 * 4);
    int*      L1       = (int*)alloc((size_t)CAP_L1 * 4);
    int*      NL2      = (int*)alloc((size_t)CAP_NL2 * 4);
    int*      NL1      = (int*)alloc((size_t)CAP_NL1 * 4);
    int*      NL0      = (int*)alloc((size_t)CAP_NL0 * 4);
    int*      PL       = (int*)alloc(256);
    int*      ctrl     = (int*)alloc(256);

    const int BN = 256;
    dim3 gN((NN + BN - 1) / BN), gE((NE + BN - 1) / BN), b(BN);

    k_init<<<gN, b, 0, stream>>>(norm_out, norm_in, flags, ctrl, PL, pair);
    k_deg_scan3<<<gE, b, 0, stream>>>(src, dst, norm_out, norm_in, flags, L3, NL2, ctrl);
    k_norm<<<gN, b, 0, stream>>>(norm_out, norm_in);
    k_scan<<<gE, b, 0, stream>>>(src, dst, flags, 4u, 2u, L2, 1, CAP_L2, NL1, 4, CAP_NL1, ctrl);
    k_scan<<<gE, b, 0, stream>>>(src, dst, flags, 2u, 1u, L1, 2, CAP_L1, NL0, 5, CAP_NL0, ctrl);
    k_prep<<<512, b, 0, stream>>>(NL0, NL1, ctrl, z, zt, bufA, bufB);

    // layer 1: bufA(x0) -> bufB(agg1) -> x1 in bufB
    k_scatter<<<512, b, 0, stream>>>(L1, ctrl, 2, CAP_L1, src, dst, norm_out, bufA, bufB);
    k_gemm<<<256, b, 0, stream>>>(NL1, ctrl, 4, CAP_NL1, norm_in, bufB, W1, b1, 1);

    // layer 2: bufB(x1) -> bufA(agg2) -> x2 in bufA
    k_zero_rows<<<64, b, 0, stream>>>(NL2, ctrl, 3, CAP_NL2, bufA);
    k_scatter<<<256, b, 0, stream>>>(L2, ctrl, 1, CAP_L2, src, dst, norm_out, bufB, bufA);
    k_gemm<<<64, b, 0, stream>>>(NL2, ctrl, 3, CAP_NL2, norm_in, bufA, W2, b2, 1);

    // layer 3: bufA(x2) -> bufB(agg3) -> x3 in bufB (no relu)
    k_zero_rows<<<1, b, 0, stream>>>(PL, ctrl, 6, 2, bufB);
    k_scatter<<<64, b, 0, stream>>>(L3, ctrl, 0, CAP_L3, src, dst, norm_out, bufA, bufB);
    k_gemm<<<1, b, 0, stream>>>(PL, ctrl, 6, 2, norm_in, bufB, W3, b3, 0);

    k_final<<<1, 64, 0, stream>>>(bufB, pair, l1w, l1b, l2w, l2b, out);
}

// Round 2
// 163.615 us; speedup vs baseline: 1.6578x; 1.6578x over previous
//
#include <hip/hip_runtime.h>

#define NN 100000
#define NE 1250000
#define HD 64

#define CAP_L3   4096
#define CAP_L2   65536
#define CAP_L1   262144
#define CAP_NL2  4096
#define CAP_NL1  65536
#define CAP_NL0  262144

// ctrl indices: 0=cntL3 1=cntL2 2=cntL1 3=cntNL2 4=cntNL1 5=cntNL0 6=cntPL(=2)
// flags bits: 3=pair, 2=NL2 (src of L3), 1=NL1 (src of L2), 0=NL0 (src of L1)

__global__ void k_init(unsigned* flags, float* cnt_in, int* ctrl, int* PL,
                       const int* __restrict__ pair) {
    int i = blockIdx.x * blockDim.x + threadIdx.x;
    int p0 = pair[0], p1 = pair[1];
    if (i < NN / 4) {
        int b = i * 4;
        uint4 f = make_uint4(0u, 0u, 0u, 0u);
        if (b     == p0 || b     == p1) f.x = 8u;
        if (b + 1 == p0 || b + 1 == p1) f.y = 8u;
        if (b + 2 == p0 || b + 2 == p1) f.z = 8u;
        if (b + 3 == p0 || b + 3 == p1) f.w = 8u;
        ((uint4*)flags)[i] = f;
    }
    if (i < 16) ctrl[i] = (i == 6) ? 2 : 0;
    if (i == 0) { PL[0] = p0; PL[1] = p1; cnt_in[p0] = 0.f; cnt_in[p1] = 0.f; }
}

// level-3 scan: edges into {pair}; mark NL2 sources (bit2), zero their counters
__global__ void k_scan3(const int* __restrict__ src, const int* __restrict__ dst,
                        const int* __restrict__ pair, unsigned* flags,
                        float* cnt_out, float* cnt_in,
                        int* L3, int* NL2, int* ctrl) {
    int t = blockIdx.x * blockDim.x + threadIdx.x;
    if (t >= NE / 4) return;
    int p0 = pair[0], p1 = pair[1];
    int4 d4 = ((const int4*)dst)[t];
#pragma unroll
    for (int k = 0; k < 4; ++k) {
        int d = (k == 0) ? d4.x : (k == 1) ? d4.y : (k == 2) ? d4.z : d4.w;
        if (d == p0 || d == p1) {
            int e = t * 4 + k;
            int s = src[e];
            int idx = atomicAdd(&ctrl[0], 1);
            if (idx < CAP_L3) L3[idx] = e;
            unsigned old = atomicOr(&flags[s], 4u);
            if (!(old & 4u)) {
                cnt_out[s] = 0.f; cnt_in[s] = 0.f;
                int j = atomicAdd(&ctrl[3], 1);
                if (j < CAP_NL2) NL2[j] = s;
            }
        }
    }
}

// generic frontier scan: collect edges whose dst has testmask, mark srcs setmask
__global__ void k_scan(const int* __restrict__ src, const int* __restrict__ dst,
                       unsigned* flags, float* cnt_out, float* cnt_in,
                       unsigned testmask, unsigned setmask,
                       int* L, int cntL_idx, int capL,
                       int* NL, int cntNL_idx, int capNL, int* ctrl) {
    int t = blockIdx.x * blockDim.x + threadIdx.x;
    if (t >= NE / 4) return;
    int4 d4 = ((const int4*)dst)[t];
#pragma unroll
    for (int k = 0; k < 4; ++k) {
        int d = (k == 0) ? d4.x : (k == 1) ? d4.y : (k == 2) ? d4.z : d4.w;
        if (flags[d] & testmask) {   // testmask bit not modified during this kernel
            int e = t * 4 + k;
            int s = src[e];
            int idx = atomicAdd(&ctrl[cntL_idx], 1);
            if (idx < capL) L[idx] = e;
            unsigned old = atomicOr(&flags[s], setmask);
            if (!(old & setmask)) {
                cnt_out[s] = 0.f; cnt_in[s] = 0.f;
                int j = atomicAdd(&ctrl[cntNL_idx], 1);
                if (j < capNL) NL[j] = s;
            }
        }
    }
}

// degrees, but only for flagged endpoints (~4K nodes instead of 100K)
__global__ void k_deg(const int* __restrict__ src, const int* __restrict__ dst,
                      const unsigned* __restrict__ flags,
                      float* cnt_out, float* cnt_in) {
    int t = blockIdx.x * blockDim.x + threadIdx.x;
    if (t >= NE / 4) return;
    int4 s4 = ((const int4*)src)[t];
    int4 d4 = ((const int4*)dst)[t];
#pragma unroll
    for (int k = 0; k < 4; ++k) {
        int s = (k == 0) ? s4.x : (k == 1) ? s4.y : (k == 2) ? s4.z : s4.w;
        int d = (k == 0) ? d4.x : (k == 1) ? d4.y : (k == 2) ? d4.z : d4.w;
        if (flags[s] & 7u)  atomicAdd(&cnt_out[s], 1.0f);   // src of some collected edge
        if (flags[d] & 14u) atomicAdd(&cnt_in[d], 1.0f);    // agg target (NL1/NL2/pair)
    }
}

// x0 = z_table[z[v]] for T0 nodes into bufA; zero T1 rows of bufB (agg target)
__global__ void k_prep(const int* __restrict__ NL0, const int* __restrict__ NL1,
                       const int* __restrict__ ctrl, const int* __restrict__ z,
                       const float* __restrict__ zt, float* bufA, float* bufB) {
    int c0 = min(ctrl[5], CAP_NL0);
    int c1 = min(ctrl[4], CAP_NL1);
    int total = (c0 + c1) * HD;
    for (int t = blockIdx.x * blockDim.x + threadIdx.x; t < total;
         t += gridDim.x * blockDim.x) {
        int r = t >> 6, lane = t & 63;
        if (r < c0) { int v = NL0[r]; bufA[v * HD + lane] = zt[z[v] * HD + lane]; }
        else        { int v = NL1[r - c0]; bufB[v * HD + lane] = 0.0f; }
    }
}

__global__ void k_zero_rows(const int* __restrict__ NL, const int* __restrict__ ctrl,
                            int cnt_idx, int cap, float* buf) {
    int cnt = min(ctrl[cnt_idx], cap);
    int total = cnt * HD;
    for (int t = blockIdx.x * blockDim.x + threadIdx.x; t < total;
         t += gridDim.x * blockDim.x) {
        int v = NL[t >> 6];
        buf[v * HD + (t & 63)] = 0.0f;
    }
}

// agg[d] += (1/sqrt(max(out_deg,1)))[s] * xin[s] over collected edge list
__global__ void k_scatter(const int* __restrict__ L, const int* __restrict__ ctrl,
                          int cnt_idx, int cap,
                          const int* __restrict__ src, const int* __restrict__ dst,
                          const float* __restrict__ cnt_out,
                          const float* __restrict__ xin, float* agg) {
    int cnt = min(ctrl[cnt_idx], cap);
    int total = cnt * HD;
    for (int t = blockIdx.x * blockDim.x + threadIdx.x; t < total;
         t += gridDim.x * blockDim.x) {
        int e = L[t >> 6], lane = t & 63;
        int s = src[e], d = dst[e];
        float w = 1.0f / sqrtf(fmaxf(cnt_out[s], 1.0f));   // wave-uniform, bit-exact norm
        atomicAdd(&agg[d * HD + lane], w * xin[s * HD + lane]);
    }
}

// row-wise: buf[v] = (buf[v]*norm_in[v]) @ W + b  (optional relu), wave per row
__global__ __launch_bounds__(256) void k_gemm(const int* __restrict__ NL,
                                              const int* __restrict__ ctrl,
                                              int cnt_idx, int cap,
                                              const float* __restrict__ cnt_in,
                                              float* buf,
                                              const float* __restrict__ W,
                                              const float* __restrict__ bias,
                                              int do_relu) {
    int cnt = min(ctrl[cnt_idx], cap);
    int gtid = blockIdx.x * blockDim.x + threadIdx.x;
    int wave = gtid >> 6, lane = gtid & 63;
    int nw = (gridDim.x * blockDim.x) >> 6;
    float wb = bias[lane];
    for (int r = wave; r < cnt; r += nw) {
        int v = NL[r];
        float nin = 1.0f / sqrtf(fmaxf(cnt_in[v], 1.0f));
        float a = buf[v * HD + lane] * nin;
        float acc = wb;
#pragma unroll
        for (int i = 0; i < HD; ++i)
            acc += __shfl(a, i, 64) * W[i * HD + lane];
        buf[v * HD + lane] = do_relu ? fmaxf(acc, 0.0f) : acc;
    }
}

// h = x3[p0]*x3[p1]; t = relu(h@lin1+b1); out = t@lin2 + b2
__global__ void k_final(const float* __restrict__ bufB, const int* __restrict__ pair,
                        const float* __restrict__ l1w, const float* __restrict__ l1b,
                        const float* __restrict__ l2w, const float* __restrict__ l2b,
                        float* out) {
    int lane = threadIdx.x;  // 64 threads
    float h = bufB[pair[0] * HD + lane] * bufB[pair[1] * HD + lane];
    float t = l1b[lane];
#pragma unroll
    for (int i = 0; i < HD; ++i)
        t += __shfl(h, i, 64) * l1w[i * HD + lane];
    t = fmaxf(t, 0.0f);
    float val = t * l2w[lane];
#pragma unroll
    for (int off = 32; off; off >>= 1)
        val += __shfl_down(val, off, 64);
    if (lane == 0) out[0] = val + l2b[0];
}

extern "C" void kernel_launch(void* const* d_in, const int* in_sizes, int n_in,
                              void* d_out, int out_size, void* d_ws, size_t ws_size,
                              hipStream_t stream) {
    const int*   z    = (const int*)d_in[0];
    const int*   src  = (const int*)d_in[1];
    const int*   dst  = (const int*)d_in[2];
    const int*   pair = (const int*)d_in[3];
    const float* zt   = (const float*)d_in[4];
    const float* W1   = (const float*)d_in[5];
    const float* b1   = (const float*)d_in[6];
    const float* W2   = (const float*)d_in[7];
    const float* b2   = (const float*)d_in[8];
    const float* W3   = (const float*)d_in[9];
    const float* b3   = (const float*)d_in[10];
    const float* l1w  = (const float*)d_in[11];
    const float* l1b  = (const float*)d_in[12];
    const float* l2w  = (const float*)d_in[13];
    const float* l2b  = (const float*)d_in[14];
    float* out = (float*)d_out;

    char* w = (char*)d_ws;
    auto alloc = [&](size_t bytes) {
        char* p = w;
        w += (bytes + 255) & ~(size_t)255;
        return p;
    };
    float*    bufA    = (float*)alloc((size_t)NN * HD * 4);
    float*    bufB    = (float*)alloc((size_t)NN * HD * 4);
    float*    cnt_out = (float*)alloc((size_t)NN * 4);
    float*    cnt_in  = (float*)alloc((size_t)NN * 4);
    unsigned* flags   = (unsigned*)alloc((size_t)NN * 4);
    int*      L3      = (int*)alloc((size_t)CAP_L3 * 4);
    int*      L2      = (int*)alloc((size_t)CAP_L2 * 4);
    int*      L1      = (int*)alloc((size_t)CAP_L1 * 4);
    int*      NL2     = (int*)alloc((size_t)CAP_NL2 * 4);
    int*      NL1     = (int*)alloc((size_t)CAP_NL1 * 4);
    int*      NL0     = (int*)alloc((size_t)CAP_NL0 * 4);
    int*      PL      = (int*)alloc(256);
    int*      ctrl    = (int*)alloc(256);

    const int BN = 256;
    dim3 b(BN);
    dim3 gN((NN + BN - 1) / BN);
    dim3 gE4((NE / 4 + BN - 1) / BN);

    k_init<<<gN, b, 0, stream>>>(flags, cnt_in, ctrl, PL, pair);
    k_scan3<<<gE4, b, 0, stream>>>(src, dst, pair, flags, cnt_out, cnt_in, L3, NL2, ctrl);
    k_scan<<<gE4, b, 0, stream>>>(src, dst, flags, cnt_out, cnt_in,
                                  4u, 2u, L2, 1, CAP_L2, NL1, 4, CAP_NL1, ctrl);
    k_scan<<<gE4, b, 0, stream>>>(src, dst, flags, cnt_out, cnt_in,
                                  2u, 1u, L1, 2, CAP_L1, NL0, 5, CAP_NL0, ctrl);
    k_deg<<<gE4, b, 0, stream>>>(src, dst, flags, cnt_out, cnt_in);
    k_prep<<<512, b, 0, stream>>>(NL0, NL1, ctrl, z, zt, bufA, bufB);

    // layer 1: bufA(x0) -> bufB(agg1) -> x1 in bufB
    k_scatter<<<512, b, 0, stream>>>(L1, ctrl, 2, CAP_L1, src, dst, cnt_out, bufA, bufB);
    k_gemm<<<256, b, 0, stream>>>(NL1, ctrl, 4, CAP_NL1, cnt_in, bufB, W1, b1, 1);

    // layer 2: bufB(x1) -> bufA(agg2) -> x2 in bufA
    k_zero_rows<<<64, b, 0, stream>>>(NL2, ctrl, 3, CAP_NL2, bufA);
    k_scatter<<<256, b, 0, stream>>>(L2, ctrl, 1, CAP_L2, src, dst, cnt_out, bufB, bufA);
    k_gemm<<<64, b, 0, stream>>>(NL2, ctrl, 3, CAP_NL2, cnt_in, bufA, W2, b2, 1);

    // layer 3: bufA(x2) -> bufB(agg3) -> x3 in bufB (no relu)
    k_zero_rows<<<1, b, 0, stream>>>(PL, ctrl, 6, 2, bufB);
    k_scatter<<<64, b, 0, stream>>>(L3, ctrl, 0, CAP_L3, src, dst, cnt_out, bufA, bufB);
    k_gemm<<<1, b, 0, stream>>>(PL, ctrl, 6, 2, cnt_in, bufB, W3, b3, 0);

    k_final<<<1, 64, 0, stream>>>(bufB, pair, l1w, l1b, l2w, l2b, out);
}